// Round 8
// baseline (1201.733 us; speedup 1.0000x reference)
//
#include <hip/hip_runtime.h>
#include <stdint.h>

#define NSTEPS 8
#define DT (1.0f / NSTEPS)

typedef __bf16 bfv8 __attribute__((ext_vector_type(8)));
typedef float f32x4 __attribute__((ext_vector_type(4)));

static __device__ __forceinline__ float fast_tanh(float x) {
  float e = __expf(2.f * x);
  return 1.f - 2.f * __builtin_amdgcn_rcpf(e + 1.f);
}
static __device__ __forceinline__ f32x4 splat4(float v) {
  f32x4 r; r[0] = v; r[1] = v; r[2] = v; r[3] = v; return r;
}

#define FENCE __builtin_amdgcn_sched_barrier(0)
// counted-vmcnt pipeline barrier: stage(s) landed (only stage(s+1) outstanding)
#define PIPEBAR()                                                  \
  do {                                                             \
    FENCE;                                                         \
    asm volatile("s_waitcnt vmcnt(4) lgkmcnt(0)" ::: "memory");    \
    __builtin_amdgcn_s_barrier();                                  \
    FENCE;                                                         \
  } while (0)
#define ENDBAR()                                                   \
  do {                                                             \
    FENCE;                                                         \
    asm volatile("s_waitcnt lgkmcnt(0)" ::: "memory");             \
    __builtin_amdgcn_s_barrier();                                  \
    FENCE;                                                         \
  } while (0)

// stage one 32KB chunk: 4 x (512 threads x 16B) global_load_lds
static __device__ __forceinline__ void stage_chunk(const char* gsrc,
                                                   char* ldst, int tid) {
#pragma unroll
  for (int i = 0; i < 4; ++i)
    __builtin_amdgcn_global_load_lds(
        (const __attribute__((address_space(1))) uint32_t*)(gsrc + i * 8192 +
                                                            tid * 16),
        (__attribute__((address_space(3))) uint32_t*)(ldst + i * 8192 +
                                                      tid * 16),
        16, 0, 0);
}

// ---------------------------------------------------------------------------
// Packed bf16 stream @ws byte 0, 34 contiguous 32KB chunks:
//  chunks 0-1 : W1P[kq][512][8],  kq<8   = W1[(kq*8+e)*512+col]
//  chunks 2-17: W2P[kc][512][8],  kc<64  = W2[(kc*8+e)*512+col]
//  chunks 18-33: GtP[kc][512][8], kc<64  = G[col, kc*8+e]
//  W3P[kc][64][8] @elem 557056 (separate, direct-loaded)
// ---------------------------------------------------------------------------
__global__ __launch_bounds__(256) void pre_kernel(
    const float* __restrict__ W1, const float* __restrict__ W2,
    const float* __restrict__ W3, __bf16* __restrict__ W1P,
    __bf16* __restrict__ W2P, __bf16* __restrict__ GtP,
    __bf16* __restrict__ W3P) {
  int t = blockIdx.x * 256 + threadIdx.x;  // 73728 frags total
  if (t < 4096) {
    int kq = t >> 9, col = t & 511;
    bfv8 o;
#pragma unroll
    for (int e = 0; e < 8; ++e) o[e] = (__bf16)W1[(kq * 8 + e) * 512 + col];
    *(bfv8*)(W1P + t * 8) = o;
  } else if (t < 36864) {
    int g = t - 4096;
    int kc = g >> 9, col = g & 511;
    bfv8 o;
#pragma unroll
    for (int e = 0; e < 8; ++e) o[e] = (__bf16)W2[(kc * 8 + e) * 512 + col];
    *(bfv8*)(W2P + g * 8) = o;
  } else if (t < 69632) {
    int g = t - 36864;
    int kc = g >> 9, j = g & 511;
    float w1c[64];
#pragma unroll
    for (int m = 0; m < 64; ++m) w1c[m] = W1[m * 512 + j];
    bfv8 o;
#pragma unroll
    for (int e = 0; e < 8; ++e) {
      int k = kc * 8 + e;
      float s = 0.f;
#pragma unroll
      for (int m = 0; m < 64; ++m) s = fmaf(w1c[m], W3[k * 64 + m], s);
      o[e] = (__bf16)(s * W2[j * 512 + k]);
    }
    *(bfv8*)(GtP + g * 8) = o;
  } else if (t < 73728) {
    int g = t - 69632;
    int kc = g >> 6, m = g & 63;
    bfv8 o;
#pragma unroll
    for (int e = 0; e < 8; ++e) o[e] = (__bf16)W3[(kc * 8 + e) * 64 + m];
    *(bfv8*)(W3P + g * 8) = o;
  }
}

// ---------------------------------------------------------------------------
// Persistent integrator: 32 blocks x 16 rows, 8 waves.
// LDS ring of 3x32KB staged 2 chunks ahead via global_load_lds; counted
// vmcnt(4) + raw s_barrier per step (never drain in main loop).
// MFMA 16x16x32 bf16 (m89): A row=lane&15,k=(lane>>4)*8+i; B col=lane&15;
// D col=lane&15,row=(lane>>4)*4+reg.
// Eval = combine | L1(2 steps) | L2(16) | TR(16) | L3(direct) | ENDBAR
// ---------------------------------------------------------------------------
__global__ __launch_bounds__(512, 2) void cnf_kernel(
    const float* __restrict__ x, const float* __restrict__ b1,
    const float* __restrict__ W1, const float* __restrict__ b2,
    const float* __restrict__ b3, const char* __restrict__ stream,
    const __bf16* __restrict__ W3P, float* __restrict__ out) {
  __shared__ char ring[3 * 32768];
  __shared__ __bf16 h1s[8192];   // [row][col] bytes, byte ^= (row&7)<<4
  __shared__ __bf16 h2s[8192];
  __shared__ __bf16 xins[1024];  // [16][64] plain
  __shared__ float kcur[1024];
  __shared__ float trbuf[16];

  const int tid = threadIdx.x;
  const int lane = tid & 63;
  const int w = tid >> 6;  // 0..7
  const int lr = lane & 15;
  const int lq = lane >> 4;
  const int rowbase = blockIdx.x * 16;
  const char* h1c = (const char*)h1s;
  const char* h2c = (const char*)h2s;

  // per-lane constants (4 col-tiles/wave in L1/L2/TR)
  float b1c[4], w1tc[4], b2c[4], b3c[4];
#pragma unroll
  for (int n = 0; n < 4; ++n) {
    const int col = (w * 4 + n) * 16 + lr;
    b1c[n] = b1[col];
    w1tc[n] = W1[64 * 512 + col];
    b2c[n] = b2[col];
    b3c[n] = b3[n * 16 + lr];
  }

  // B-fragment byte offset within any chunk: lq*8192 + ((w*4+n)*16+lr)*16
  const int bbase = lq * 8192 + w * 1024 + lr * 16;

  // per-thread RK4 state: elements tid and tid+512 of [16][64]
  float xbA = 0.f, xbB = 0.f, kaA = 0.f, kaB = 0.f, ldv = 0.f, ldacc = 0.f;

  int sc = 0;  // ring consume slot (cycles mod 3 across the whole kernel)
  stage_chunk(stream, ring, tid);                  // chunk 0 -> slot 0
  stage_chunk(stream + 32768, ring + 32768, tid);  // chunk 1 -> slot 1

#define STEP_HEAD(T_NEXT)                                                \
  do {                                                                   \
    PIPEBAR();                                                           \
    int ss_ = sc + 2; if (ss_ >= 3) ss_ -= 3;                            \
    stage_chunk(stream + (T_NEXT) * 32768, ring + ss_ * 32768, tid);     \
  } while (0)
#define STEP_TAIL() do { sc = (sc + 1 == 3) ? 0 : sc + 1; } while (0)

#pragma unroll 1
  for (int ev = 0; ev <= 4 * NSTEPS; ++ev) {
    // ---------------- combine (per-thread registers + LDS kcur) ----------
    {
      float xwA, xwB;
      if (ev == 0) {
        xbA = x[rowbase * 64 + tid];
        xbB = x[rowbase * 64 + 512 + tid];
        xwA = xbA; xwB = xbB;
        kcur[tid] = 0.f; kcur[tid + 512] = 0.f;
        if (tid < 16) trbuf[tid] = 0.f;
      } else {
        const int gp = (ev - 1) & 3;
        const float k0 = kcur[tid], k1 = kcur[tid + 512];
        kcur[tid] = 0.f; kcur[tid + 512] = 0.f;
        float tv = 0.f;
        if (tid < 16) { tv = trbuf[tid]; trbuf[tid] = 0.f; }
        if (gp < 3) {
          const float wg = (gp == 0) ? 1.f : 2.f;
          const float cn = (gp == 2) ? DT : 0.5f * DT;
          kaA += wg * k0; kaB += wg * k1;
          xwA = xbA + cn * k0; xwB = xbB + cn * k1;
          if (tid < 16) ldacc += wg * tv;
        } else {
          xbA += (DT / 6.f) * (kaA + k0);
          xbB += (DT / 6.f) * (kaB + k1);
          kaA = 0.f; kaB = 0.f;
          xwA = xbA; xwB = xbB;
          if (tid < 16) { ldv -= (DT / 6.f) * (ldacc + tv); ldacc = 0.f; }
        }
      }
      if (ev == 4 * NSTEPS) {
        out[rowbase * 64 + tid] = xwA;
        out[rowbase * 64 + 512 + tid] = xwB;
        if (tid < 16) out[512 * 64 + rowbase + tid] = ldv;
        break;
      }
      xins[tid] = (__bf16)xwA;
      xins[tid + 512] = (__bf16)xwB;
    }

    const int g = ev & 3;
    const float tval =
        (ev >> 2) * DT + ((g == 0) ? 0.f : (g == 3) ? DT : 0.5f * DT);
    f32x4 C[4];

    // ---------------- L1: steps 0,1 (chunks 0,1 = W1P) --------------------
    {
      STEP_HEAD(2);
      const bfv8 a0 = *(const bfv8*)&xins[lr * 64 + lq * 8];
      const char* bs = ring + sc * 32768 + bbase;
#pragma unroll
      for (int n = 0; n < 4; ++n) {
        C[n] = splat4(b1c[n] + tval * w1tc[n]);
        C[n] = __builtin_amdgcn_mfma_f32_16x16x32_bf16(
            a0, *(const bfv8*)(bs + n * 256), C[n], 0, 0, 0);
      }
      STEP_TAIL();
    }
    {
      STEP_HEAD(3);
      const bfv8 a1 = *(const bfv8*)&xins[lr * 64 + 32 + lq * 8];
      const char* bs = ring + sc * 32768 + bbase;
#pragma unroll
      for (int n = 0; n < 4; ++n) {
        C[n] = __builtin_amdgcn_mfma_f32_16x16x32_bf16(
            a1, *(const bfv8*)(bs + n * 256), C[n], 0, 0, 0);
#pragma unroll
        for (int r = 0; r < 4; ++r) {
          const int row = lq * 4 + r;
          const int col = (w * 4 + n) * 16 + lr;
          *(__bf16*)((char*)h1s + row * 1024 + ((col * 2) ^ ((row & 7) << 4))) =
              (__bf16)fast_tanh(C[n][r]);
        }
      }
      STEP_TAIL();
    }

    // ---------------- L2: steps 2..17 (chunks 2..17 = W2P) ----------------
#pragma unroll
    for (int c = 0; c < 16; ++c) {
      STEP_HEAD(c + 4);  // max 19 < 34, no wrap
      if (c == 0) {
#pragma unroll
        for (int n = 0; n < 4; ++n) C[n] = splat4(0.f);
      }
      const bfv8 A = *(const bfv8*)(h1c + lr * 1024 +
                                    (((c * 64) + lq * 16) ^ ((lr & 7) << 4)));
      const char* bs = ring + sc * 32768 + bbase;
#pragma unroll
      for (int n = 0; n < 4; ++n)
        C[n] = __builtin_amdgcn_mfma_f32_16x16x32_bf16(
            A, *(const bfv8*)(bs + n * 256), C[n], 0, 0, 0);
      if (c == 15) {
#pragma unroll
        for (int n = 0; n < 4; ++n)
#pragma unroll
          for (int r = 0; r < 4; ++r) {
            const int row = lq * 4 + r;
            const int col = (w * 4 + n) * 16 + lr;
            const float tv = fast_tanh(C[n][r] + b2c[n]);
            *(__bf16*)((char*)h2s + row * 1024 +
                       ((col * 2) ^ ((row & 7) << 4))) = (__bf16)tv;
          }
      }
      STEP_TAIL();
    }

    // ---------------- TR: steps 18..33 (chunks 18..33 = GtP) --------------
#pragma unroll
    for (int c = 0; c < 16; ++c) {
      STEP_HEAD((c < 14) ? 20 + c : c - 14);  // cyclic: stages next eval 0,1
      if (c == 0) {
#pragma unroll
        for (int n = 0; n < 4; ++n) C[n] = splat4(0.f);
      }
      const bfv8 hv = *(const bfv8*)(h2c + lr * 1024 +
                                     (((c * 64) + lq * 16) ^ ((lr & 7) << 4)));
      bfv8 av;
#pragma unroll
      for (int e = 0; e < 8; ++e) {
        const float tv = (float)hv[e];
        av[e] = (__bf16)(1.f - tv * tv);
      }
      const char* bs = ring + sc * 32768 + bbase;
#pragma unroll
      for (int n = 0; n < 4; ++n)
        C[n] = __builtin_amdgcn_mfma_f32_16x16x32_bf16(
            av, *(const bfv8*)(bs + n * 256), C[n], 0, 0, 0);
      if (c == 15) {
        float pacc[4] = {0.f, 0.f, 0.f, 0.f};
#pragma unroll
        for (int n = 0; n < 4; ++n)
#pragma unroll
          for (int r = 0; r < 4; ++r) {
            const int row = lq * 4 + r;
            const int col = (w * 4 + n) * 16 + lr;
            const float h1v = (float)*(const __bf16*)(
                h1c + row * 1024 + ((col * 2) ^ ((row & 7) << 4)));
            pacc[r] += C[n][r] * (1.f - h1v * h1v);
          }
#pragma unroll
        for (int r = 0; r < 4; ++r) {
          float p = pacc[r];
          p += __shfl_xor(p, 1);
          p += __shfl_xor(p, 2);
          p += __shfl_xor(p, 4);
          p += __shfl_xor(p, 8);
          if (lr == 0) atomicAdd(&trbuf[lq * 4 + r], p);
        }
      }
      STEP_TAIL();
    }

    // ------- L3 (direct loads, k-split across waves): kcur += h2@W3+b3 ----
    {
      bfv8 A2[2];
#pragma unroll
      for (int h = 0; h < 2; ++h)
        A2[h] = *(const bfv8*)(h2c + lr * 1024 +
                               ((w * 128 + h * 64 + lq * 16) ^
                                ((lr & 7) << 4)));
      f32x4 C3;
#pragma unroll
      for (int f = 0; f < 8; ++f) {
        const int mt = f >> 1, h = f & 1;
        if (h == 0) C3 = splat4((w == 0) ? b3c[mt] : 0.f);
        const bfv8 B = *(const bfv8*)(W3P + (w * 8 + h * 4 + lq) * 512 +
                                      (mt * 16 + lr) * 8);
        C3 = __builtin_amdgcn_mfma_f32_16x16x32_bf16(A2[h], B, C3, 0, 0, 0);
        if (h == 1) {
#pragma unroll
          for (int r = 0; r < 4; ++r)
            atomicAdd(&kcur[(lq * 4 + r) * 64 + mt * 16 + lr], C3[r]);
        }
      }
    }
    ENDBAR();
  }
}

extern "C" void kernel_launch(void* const* d_in, const int* in_sizes, int n_in,
                              void* d_out, int out_size, void* d_ws,
                              size_t ws_size, hipStream_t stream) {
  const float* x = (const float*)d_in[0];
  const float* W1 = (const float*)d_in[1];
  const float* b1 = (const float*)d_in[2];
  const float* W2 = (const float*)d_in[3];
  const float* b2 = (const float*)d_in[4];
  const float* W3 = (const float*)d_in[5];
  const float* b3 = (const float*)d_in[6];
  float* out = (float*)d_out;
  __bf16* wsb = (__bf16*)d_ws;

  __bf16* W1P = wsb;            // bytes 0..65535        (chunks 0-1)
  __bf16* W2P = wsb + 32768;    // bytes 65536..589823   (chunks 2-17)
  __bf16* GtP = wsb + 294912;   // bytes 589824..1114111 (chunks 18-33)
  __bf16* W3P = wsb + 557056;   // separate 64KB

  pre_kernel<<<288, 256, 0, stream>>>(W1, W2, W3, W1P, W2P, GtP, W3P);
  cnf_kernel<<<32, 512, 0, stream>>>(x, b1, W1, b2, b3, (const char*)wsb, W3P,
                                     out);
}